// Round 6
// baseline (663.164 us; speedup 1.0000x reference)
//
#include <hip/hip_runtime.h>

typedef _Float16 f16;
typedef f16  f16x8 __attribute__((ext_vector_type(8)));
typedef f16  f16x4 __attribute__((ext_vector_type(4)));
typedef float f32x4 __attribute__((ext_vector_type(4)));

#define HH 540
#define WW 960
#define HWPIX (HH*WW)

// ws layout (bytes):
//   wpk @ 0: prepacked f16 weights (w1p 4096 | w2p 36864 | w3p 18432 | w4p 27648)
//   f1  @ 131072            : 66,355,200
//   f2  @ 131072+66355200   : 33,177,600
//   f3  @ 131072            : aliases f1 (f1 dead once conv3 runs; stream-ordered)

// ------------------------------------------------------------ weight prepack
__global__ __launch_bounds__(256) void prepack_k(const float* __restrict__ w1,
        const float* __restrict__ w2, const float* __restrict__ w3,
        const float* __restrict__ w4, f16* __restrict__ ws) {
    int i = blockIdx.x*256 + threadIdx.x;
    f16* w1p = ws;
    f16* w2p = ws + 2048;
    f16* w3p = ws + 2048 + 18432;
    f16* w4p = ws + 2048 + 18432 + 9216;
    if (i < 2048) {
        int k = i & 31, co = i >> 5;
        w1p[i] = (f16)(k < 25 ? w1[co*25 + k] : 0.f);
    } else if (i < 2048 + 18432) {
        int j = i - 2048;
        int ci = j & 63; int rest = j >> 6; int co = rest & 31; int tap = rest >> 5;
        w2p[j] = (f16)w2[(co*64 + ci)*9 + tap];
    } else if (i < 2048 + 18432 + 9216) {
        int j = i - (2048 + 18432);
        int ci = j & 31; int rest = j >> 5; int co = rest & 31; int tap = rest >> 5;
        w3p[j] = (f16)w3[(co*32 + ci)*9 + tap];
    } else if (i < 2048 + 18432 + 9216 + 13824) {
        int j = i - (2048 + 18432 + 9216);
        int ci = j & 31; int rest = j >> 5; int co = rest % 48; int tap = rest / 48;
        w4p[j] = (f16)(co < 37 ? w4[(co*32 + ci)*9 + tap] : 0.f);
    }
}

// ------------------------------------------------------------ conv1 (MFMA)
// 1->64, 5x5 pad2, PReLU. A=weights[co][k(25 pad 32)], B=pixels. LDS-staged x tile.
__global__ __launch_bounds__(256, 4) void conv1m_k(const float* __restrict__ xin,
        const f16* __restrict__ w1p, const float* __restrict__ bg,
        const float* __restrict__ pa, f16* __restrict__ f1) {
    __shared__ float tile[8*72];
    const int tid = threadIdx.x;
    const int w = tid >> 6, lane = tid & 63, l16 = lane & 15, quad = lane >> 4;
    const int trow = blockIdx.x / 15, tcol = blockIdx.x % 15;
    const int r = trow*4 + w, x0 = tcol*64;
    const float alpha = pa[0];

    for (int i = tid; i < 8*72; i += 256) {
        int rr = i / 72, xl = i - rr*72;
        int gy = trow*4 + rr - 2, gx = x0 + xl - 2;
        float v = 0.f;
        if ((unsigned)gy < (unsigned)HH && (unsigned)gx < (unsigned)WW)
            v = xin[gy*WW + gx];
        tile[i] = v;
    }

    f16x8 Wf[4];
#pragma unroll
    for (int t = 0; t < 4; t++)
        Wf[t] = *(const f16x8*)&w1p[(t*16 + l16)*32 + quad*8];

    f32x4 acc[4][4];
#pragma unroll
    for (int t = 0; t < 4; t++) {
        f32x4 b4 = *(const f32x4*)&bg[t*16 + quad*4];
#pragma unroll
        for (int mt = 0; mt < 4; mt++) acc[mt][t] = b4;
    }

    int offj[8];
    bool okj[8];
#pragma unroll
    for (int j = 0; j < 8; j++) {
        int t = quad*8 + j;
        int ky = t / 5, kx = t - ky*5;
        offj[j] = (w + ky)*72 + l16 + kx;
        okj[j] = (t < 25);
    }
    __syncthreads();

#pragma unroll
    for (int mt = 0; mt < 4; mt++) {
        f16x8 a;
#pragma unroll
        for (int j = 0; j < 8; j++)
            a[j] = okj[j] ? (f16)tile[offj[j] + mt*16] : (f16)0.f;
#pragma unroll
        for (int t = 0; t < 4; t++)
            acc[mt][t] = __builtin_amdgcn_mfma_f32_16x16x32_f16(Wf[t], a, acc[mt][t], 0,0,0);
    }

#pragma unroll
    for (int mt = 0; mt < 4; mt++) {
        int gx = x0 + mt*16 + l16;
        size_t base = ((size_t)r*WW + gx)*64;
#pragma unroll
        for (int t = 0; t < 4; t++) {
            f16x4 h;
#pragma unroll
            for (int r4 = 0; r4 < 4; r4++) {
                float v = acc[mt][t][r4];
                v = (v >= 0.f) ? v : alpha*v;
                h[r4] = (f16)v;
            }
            *(f16x4*)&f1[base + t*16 + quad*4] = h;
        }
    }
}

// ------------------------------------------------------------ conv2/conv3 (MFMA, dy-reuse)
// CI->32, 3x3 pad1, PReLU. Block tile = 16 out rows x 16 px; wave w -> rows 4w..4w+3.
// Each pixel-row b128 read feeds up to 3 dy-accs x 2 nt = 6 MFMAs (avg 4).
// Weights kc-outer: 18 live frags, no spills. LDS XOR-swizzled, conflict-free.
template<int CI, int MINW>
__global__ __launch_bounds__(256, MINW) void convM_k(const f16* __restrict__ fin,
        const f16* __restrict__ wp, const float* __restrict__ bg,
        const float* __restrict__ pa, f16* __restrict__ fout) {
    constexpr int KC  = CI/32;
    constexpr int C16 = CI/8;
    constexpr int SWZ = C16 - 1;
    constexpr int TROWS = 18, TPX = 18;
    constexpr int CHUNKS = TROWS*TPX*C16;
    __shared__ __align__(16) f16 tile[TROWS*TPX*CI];

    const int tid = threadIdx.x;
    const int w = tid >> 6, lane = tid & 63, l16 = lane & 15, quad = lane >> 4;
    const int trow = blockIdx.x / 60, tcol = blockIdx.x % 60;
    const int ytile = trow*16, x0 = tcol*16;
    const float alpha = pa[0];

    // stage 18 rows x 18 px (zero halo), swizzled
#pragma unroll
    for (int it = 0; it < (CHUNKS + 255)/256; it++) {
        int i = it*256 + tid;
        if (i < CHUNKS) {
            int c8 = i & SWZ; int rest = i / C16; int xl = rest % TPX; int rr = rest / TPX;
            int gy = ytile + rr - 1, gx = x0 + xl - 1;
            uint4 v = make_uint4(0u,0u,0u,0u);
            if ((unsigned)gy < (unsigned)HH && (unsigned)gx < (unsigned)WW)
                v = *(const uint4*)&fin[((size_t)gy*WW + gx)*CI + c8*8];
            *(uint4*)&tile[(rr*TPX + xl)*CI + ((c8 ^ (xl & SWZ))*8)] = v;
        }
    }

    f32x4 acc[4][2];
    {
        f32x4 b0 = *(const f32x4*)&bg[quad*4];
        f32x4 b1 = *(const f32x4*)&bg[16 + quad*4];
#pragma unroll
        for (int i = 0; i < 4; i++) { acc[i][0] = b0; acc[i][1] = b1; }
    }
    __syncthreads();

#pragma unroll
    for (int kc = 0; kc < KC; kc++) {
        f16x8 Wf[9][2];
#pragma unroll
        for (int tap = 0; tap < 9; tap++)
#pragma unroll
            for (int t = 0; t < 2; t++)
                Wf[tap][t] = *(const f16x8*)&wp[(tap*32 + t*16 + l16)*CI + kc*32 + quad*8];
#pragma unroll
        for (int pr = 0; pr < 6; pr++) {
            int rr = 4*w + pr;
#pragma unroll
            for (int dx = 0; dx < 3; dx++) {
                int xl = l16 + dx;
                f16x8 b = *(const f16x8*)&tile[(rr*TPX + xl)*CI + (((kc*4 + quad) ^ (xl & SWZ))*8)];
#pragma unroll
                for (int dy = 0; dy < 3; dy++) {
                    int i = pr - dy;
                    if (i >= 0 && i < 4) {
                        acc[i][0] = __builtin_amdgcn_mfma_f32_16x16x32_f16(Wf[dy*3+dx][0], b, acc[i][0], 0,0,0);
                        acc[i][1] = __builtin_amdgcn_mfma_f32_16x16x32_f16(Wf[dy*3+dx][1], b, acc[i][1], 0,0,0);
                    }
                }
            }
        }
    }

#pragma unroll
    for (int i = 0; i < 4; i++) {
        int r = ytile + 4*w + i;
        if (r < HH) {
            int gx = x0 + l16;
            size_t bo = ((size_t)r*WW + gx)*32;
#pragma unroll
            for (int t = 0; t < 2; t++) {
                f16x4 h;
#pragma unroll
                for (int r4 = 0; r4 < 4; r4++) {
                    float v = acc[i][t][r4];
                    v = (v >= 0.f) ? v : alpha*v;
                    h[r4] = (f16)v;
                }
                *(f16x4*)&fout[bo + t*16 + quad*4] = h;
            }
        }
    }
}

// ------------------------------------------------------------ conv4 (MFMA, dy-reuse) + head
// 32->37 (pad 48 = 3 nt), 3x3 pad1, bias, no act; fused pixel head.
// Block tile = 8 rows x 16 px; wave w -> rows 2w, 2w+1. fp32 head buf stride 42.
__global__ __launch_bounds__(256, 3) void conv4m_k(const f16* __restrict__ fin,
        const f16* __restrict__ wp, const float* __restrict__ bg,
        float* __restrict__ outp) {
    constexpr int CI = 32, C16 = 4, SWZ = 3;
    constexpr int TROWS = 10, TPX = 18;
    constexpr int CHUNKS = TROWS*TPX*C16;
    __shared__ __align__(16) char smem[128*42*4];   // 21504B >= tile 11520B
    f16*   tile = (f16*)smem;
    float* olds = (float*)smem;

    const int tid = threadIdx.x;
    const int w = tid >> 6, lane = tid & 63, l16 = lane & 15, quad = lane >> 4;
    const int trow = blockIdx.x / 60, tcol = blockIdx.x % 60;
    const int ytile = trow*8, x0 = tcol*16;

#pragma unroll
    for (int it = 0; it < (CHUNKS + 255)/256; it++) {
        int i = it*256 + tid;
        if (i < CHUNKS) {
            int c8 = i & SWZ; int rest = i >> 2; int xl = rest % TPX; int rr = rest / TPX;
            int gy = ytile + rr - 1, gx = x0 + xl - 1;
            uint4 v = make_uint4(0u,0u,0u,0u);
            if ((unsigned)gy < (unsigned)HH && (unsigned)gx < (unsigned)WW)
                v = *(const uint4*)&fin[((size_t)gy*WW + gx)*CI + c8*8];
            *(uint4*)&tile[(rr*TPX + xl)*CI + ((c8 ^ (xl & SWZ))*8)] = v;
        }
    }

    f16x8 Wf[9][3];
#pragma unroll
    for (int tap = 0; tap < 9; tap++)
#pragma unroll
        for (int t = 0; t < 3; t++)
            Wf[tap][t] = *(const f16x8*)&wp[(tap*48 + t*16 + l16)*32 + quad*8];

    f32x4 acc[2][3];
    {
        f32x4 b0 = *(const f32x4*)&bg[quad*4];
        f32x4 b1 = *(const f32x4*)&bg[16 + quad*4];
        f32x4 b2;
#pragma unroll
        for (int r4 = 0; r4 < 4; r4++) {
            int co = 32 + quad*4 + r4;
            b2[r4] = (co < 37) ? bg[co] : 0.f;
        }
#pragma unroll
        for (int i = 0; i < 2; i++) { acc[i][0] = b0; acc[i][1] = b1; acc[i][2] = b2; }
    }
    __syncthreads();

#pragma unroll
    for (int pr = 0; pr < 4; pr++) {
        int rr = 2*w + pr;
#pragma unroll
        for (int dx = 0; dx < 3; dx++) {
            int xl = l16 + dx;
            f16x8 b = *(const f16x8*)&tile[(rr*TPX + xl)*CI + ((quad ^ (xl & SWZ))*8)];
#pragma unroll
            for (int dy = 0; dy < 3; dy++) {
                int i = pr - dy;
                if (i >= 0 && i < 2) {
#pragma unroll
                    for (int t = 0; t < 3; t++)
                        acc[i][t] = __builtin_amdgcn_mfma_f32_16x16x32_f16(Wf[dy*3+dx][t], b, acc[i][t], 0,0,0);
                }
            }
        }
    }
    __syncthreads();   // tile dead; reuse as olds

    // W (37ch fp32) -> LDS [128 px][42]
#pragma unroll
    for (int i = 0; i < 2; i++) {
        float* dst = &olds[((2*w + i)*16 + l16)*42];
#pragma unroll
        for (int t = 0; t < 3; t++) {
            if (t < 2 || quad < 2) {
                int cb = t*16 + quad*4;
                *(float2*)&dst[cb]   = make_float2(acc[i][t][0], acc[i][t][1]);
                *(float2*)&dst[cb+2] = make_float2(acc[i][t][2], acc[i][t][3]);
            }
        }
    }
    __syncthreads();

    // head: 1 px/thread for tids < 128
    if (tid < 128) {
        int rloc = tid >> 4, xx = tid & 15;
        int gy = ytile + rloc, gx = x0 + xx;
        if (gy < HH) {
            const float* Wp = &olds[tid*42];
            float base = Wp[36];
            float o0 = base, o1 = base, o2 = base, o3 = base;
#pragma unroll
            for (int j = 0; j < 12; j++) {
                float u  = Wp[2*j];
                float v  = Wp[2*j+1];
                float w1 = Wp[24+j];
                float s = 0.25f*(u+v);
                float d = 0.25f*(v-u);
                o0 += fmaxf(d, 0.f)*w1;
                o1 += fmaxf(s, 0.f)*w1;
                o2 += fmaxf(-s, 0.f)*w1;
                o3 += fmaxf(-d, 0.f)*w1;
            }
            *(float2*)(outp + (size_t)(2*gy)*(2*WW) + 2*gx)   = make_float2(o0, o1);
            *(float2*)(outp + (size_t)(2*gy+1)*(2*WW) + 2*gx) = make_float2(o2, o3);
        }
    }
}

extern "C" void kernel_launch(void* const* d_in, const int* in_sizes, int n_in,
                              void* d_out, int out_size, void* d_ws, size_t ws_size,
                              hipStream_t stream) {
    const float* x  = (const float*)d_in[0];
    const float* w1 = (const float*)d_in[1];
    const float* b1 = (const float*)d_in[2];
    const float* w2 = (const float*)d_in[3];
    const float* b2 = (const float*)d_in[4];
    const float* w3 = (const float*)d_in[5];
    const float* b3 = (const float*)d_in[6];
    const float* w4 = (const float*)d_in[7];
    const float* b4 = (const float*)d_in[8];
    const float* pa = (const float*)d_in[9];
    float* outp = (float*)d_out;

    char* ws = (char*)d_ws;
    f16* wpk = (f16*)ws;
    const f16* w1p = wpk;
    const f16* w2p = wpk + 2048;
    const f16* w3p = wpk + 2048 + 18432;
    const f16* w4p = wpk + 2048 + 18432 + 9216;
    f16* f1 = (f16*)(ws + 131072);
    f16* f2 = (f16*)(ws + 131072 + 66355200);
    f16* f3 = f1;   // alias: f1 dead by conv3 (stream-ordered)

    prepack_k<<<dim3(170), 256, 0, stream>>>(w1, w2, w3, w4, wpk);

    const int NT1 = 2025;   // (540/4) * (960/64)
    const int NT2 = 34*60;  // 16-row groups x 16-px cols
    const int NT4 = 68*60;  // 8-row groups x 16-px cols
    for (int b = 0; b < 4; b++) {
        conv1m_k<<<dim3(NT1), 256, 0, stream>>>(x + (size_t)b*HWPIX, w1p, b1, pa, f1);
        convM_k<64,3><<<dim3(NT2), 256, 0, stream>>>(f1, w2p, b2, pa, f2);
        convM_k<32,3><<<dim3(NT2), 256, 0, stream>>>(f2, w3p, b3, pa, f3);
        conv4m_k<<<dim3(NT4), 256, 0, stream>>>(f3, w4p, b4, outp + (size_t)b*4*HWPIX);
    }
}

// Round 7
// 484.870 us; speedup vs baseline: 1.3677x; 1.3677x over previous
//
#include <hip/hip_runtime.h>

typedef _Float16 f16;
typedef f16  f16x8 __attribute__((ext_vector_type(8)));
typedef f16  f16x4 __attribute__((ext_vector_type(4)));
typedef float f32x4 __attribute__((ext_vector_type(4)));

#define HH 540
#define WW 960
#define HWPIX (HH*WW)

// ws layout (bytes):
//   wpk @ 0: prepacked f16 weights (w1p 4096 | w2p 36864 | w3p 18432 | w4p 27648)
//   f2  @ 131072 : 540*960*32*2 = 33,177,600   (only surviving intermediate)

// ------------------------------------------------------------ weight prepack
__global__ __launch_bounds__(256) void prepack_k(const float* __restrict__ w1,
        const float* __restrict__ w2, const float* __restrict__ w3,
        const float* __restrict__ w4, f16* __restrict__ ws) {
    int i = blockIdx.x*256 + threadIdx.x;
    f16* w1p = ws;
    f16* w2p = ws + 2048;
    f16* w3p = ws + 2048 + 18432;
    f16* w4p = ws + 2048 + 18432 + 9216;
    if (i < 2048) {
        int k = i & 31, co = i >> 5;
        w1p[i] = (f16)(k < 25 ? w1[co*25 + k] : 0.f);
    } else if (i < 2048 + 18432) {
        int j = i - 2048;
        int ci = j & 63; int rest = j >> 6; int co = rest & 31; int tap = rest >> 5;
        w2p[j] = (f16)w2[(co*64 + ci)*9 + tap];
    } else if (i < 2048 + 18432 + 9216) {
        int j = i - (2048 + 18432);
        int ci = j & 31; int rest = j >> 5; int co = rest & 31; int tap = rest >> 5;
        w3p[j] = (f16)w3[(co*32 + ci)*9 + tap];
    } else if (i < 2048 + 18432 + 9216 + 13824) {
        int j = i - (2048 + 18432 + 9216);
        int ci = j & 31; int rest = j >> 5; int co = rest % 48; int tap = rest / 48;
        w4p[j] = (f16)(co < 37 ? w4[(co*32 + ci)*9 + tap] : 0.f);
    }
}

// ------------------------------------------------------------ fuseA: conv1 + conv2
// Out tile 16x16 of f2. x tile 22x22 (origin ytile-3,x0-3) -> conv1 (MFMA,
// A=weights 64co x K32) -> f1 LDS tile 18x18x64 (origin ytile-1,x0-1, swizzled,
// out-of-image px zeroed) -> conv2 (MFMA dy-reuse) -> f2 global (PReLU, packed).
__global__ __launch_bounds__(256, 3) void fuseA_k(const float* __restrict__ xin,
        const f16* __restrict__ w1p, const float* __restrict__ b1,
        const f16* __restrict__ w2p, const float* __restrict__ b2,
        const float* __restrict__ pa, f16* __restrict__ f2out) {
    __shared__ __align__(16) float xt[22*22];
    __shared__ __align__(16) f16 f1t[324*64];
    const int tid = threadIdx.x;
    const int w = tid >> 6, lane = tid & 63, l16 = lane & 15, quad = lane >> 4;
    const int trow = blockIdx.x / 60, tcol = blockIdx.x % 60;
    const int ytile = trow*16, x0 = tcol*16;
    const float alpha = pa[0];

    // stage x tile (zero halo)
    for (int i = tid; i < 484; i += 256) {
        int rr = i / 22, xl = i - rr*22;
        int gy = ytile - 3 + rr, gx = x0 - 3 + xl;
        float v = 0.f;
        if ((unsigned)gy < (unsigned)HH && (unsigned)gx < (unsigned)WW)
            v = xin[gy*WW + gx];
        xt[i] = v;
    }

    // conv1 weight frags: A[m=co(l16 within t-tile)][k=quad*8+j]
    f16x8 W1f[4];
#pragma unroll
    for (int t = 0; t < 4; t++)
        W1f[t] = *(const f16x8*)&w1p[(t*16 + l16)*32 + quad*8];

    int tky[8], tkx[8]; bool tok[8];
#pragma unroll
    for (int j = 0; j < 8; j++) {
        int t = quad*8 + j;
        tok[j] = (t < 25);
        tky[j] = t / 5; tkx[j] = t - (t/5)*5;
    }
    __syncthreads();

    // conv1: 21 groups of 16 px over 324 px (18x18)
    for (int g = w; g < 21; g += 4) {
        int p = g*16 + l16;
        bool pin = p < 324;
        int pc = pin ? p : 323;
        int rr = pc / 18, xl = pc - rr*18;
        f16x8 a;
#pragma unroll
        for (int j = 0; j < 8; j++)
            a[j] = tok[j] ? (f16)xt[(rr + tky[j])*22 + xl + tkx[j]] : (f16)0.f;
        f32x4 acc1[4];
#pragma unroll
        for (int t = 0; t < 4; t++) acc1[t] = *(const f32x4*)&b1[t*16 + quad*4];
#pragma unroll
        for (int t = 0; t < 4; t++)
            acc1[t] = __builtin_amdgcn_mfma_f32_16x16x32_f16(W1f[t], a, acc1[t], 0,0,0);
        int fy = ytile - 1 + rr, fx = x0 - 1 + xl;
        bool img = (unsigned)fy < (unsigned)HH && (unsigned)fx < (unsigned)WW;
        if (pin) {
#pragma unroll
            for (int t = 0; t < 4; t++) {
                f16x4 h;
#pragma unroll
                for (int r4 = 0; r4 < 4; r4++) {
                    float v = acc1[t][r4];
                    v = (v >= 0.f) ? v : alpha*v;
                    h[r4] = img ? (f16)v : (f16)0.f;
                }
                int c8w = t*2 + (quad >> 1);
                *(f16x4*)&f1t[p*64 + ((c8w ^ (xl & 7))*8) + (quad & 1)*4] = h;
            }
        }
    }
    __syncthreads();

    // conv2: wave w -> out rows 4w..4w+3; kc-outer weights; dy-reuse
    f32x4 acc[4][2];
    {
        f32x4 c0 = *(const f32x4*)&b2[quad*4];
        f32x4 c1 = *(const f32x4*)&b2[16 + quad*4];
#pragma unroll
        for (int i = 0; i < 4; i++) { acc[i][0] = c0; acc[i][1] = c1; }
    }
#pragma unroll
    for (int kc = 0; kc < 2; kc++) {
        f16x8 Wf[9][2];
#pragma unroll
        for (int tap = 0; tap < 9; tap++)
#pragma unroll
            for (int t = 0; t < 2; t++)
                Wf[tap][t] = *(const f16x8*)&w2p[(tap*32 + t*16 + l16)*64 + kc*32 + quad*8];
#pragma unroll
        for (int pr = 0; pr < 6; pr++) {
            int rr = 4*w + pr;
#pragma unroll
            for (int dx = 0; dx < 3; dx++) {
                int xl = l16 + dx;
                f16x8 b = *(const f16x8*)&f1t[(rr*18 + xl)*64 + (((kc*4 + quad) ^ (xl & 7))*8)];
#pragma unroll
                for (int dy = 0; dy < 3; dy++) {
                    int i = pr - dy;
                    if (i >= 0 && i < 4) {
                        acc[i][0] = __builtin_amdgcn_mfma_f32_16x16x32_f16(Wf[dy*3+dx][0], b, acc[i][0], 0,0,0);
                        acc[i][1] = __builtin_amdgcn_mfma_f32_16x16x32_f16(Wf[dy*3+dx][1], b, acc[i][1], 0,0,0);
                    }
                }
            }
        }
    }
#pragma unroll
    for (int i = 0; i < 4; i++) {
        int r = ytile + 4*w + i;
        if (r < HH) {
            size_t bo = ((size_t)r*WW + x0 + l16)*32;
#pragma unroll
            for (int t = 0; t < 2; t++) {
                f16x4 h;
#pragma unroll
                for (int r4 = 0; r4 < 4; r4++) {
                    float v = acc[i][t][r4];
                    v = (v >= 0.f) ? v : alpha*v;
                    h[r4] = (f16)v;
                }
                *(f16x4*)&f2out[bo + t*16 + quad*4] = h;
            }
        }
    }
}

// ------------------------------------------------------------ fuseB: conv3 + conv4 + head
// Out tile 16x16. f2 tile 20x20x32 (origin ytile-2,x0-2) -> conv3 -> f3 LDS tile
// 18x18x32 (out-of-image zeroed) -> conv4 (dy-outer weights) -> head (LDS fp32,
// aliases dead tiles) -> output.
__global__ __launch_bounds__(256, 3) void fuseB_k(const f16* __restrict__ f2in,
        const f16* __restrict__ w3p, const float* __restrict__ b3,
        const f16* __restrict__ w4p, const float* __restrict__ b4,
        const float* __restrict__ pa, float* __restrict__ outp) {
    __shared__ __align__(16) char smem[46336];
    f16*   f2t   = (f16*)smem;             // 25600 B
    f16*   f3t   = (f16*)(smem + 25600);   // 20736 B
    float* headb = (float*)smem;           // 43008 B (valid after f3t dead)

    const int tid = threadIdx.x;
    const int w = tid >> 6, lane = tid & 63, l16 = lane & 15, quad = lane >> 4;
    const int trow = blockIdx.x / 60, tcol = blockIdx.x % 60;
    const int ytile = trow*16, x0 = tcol*16;
    const float alpha = pa[0];

    // stage f2 tile 20x20 (zero halo), swizzled
#pragma unroll
    for (int it = 0; it < 7; it++) {
        int i = it*256 + tid;
        if (i < 1600) {
            int c8 = i & 3; int rest = i >> 2; int xl = rest % 20; int rr = rest / 20;
            int gy = ytile - 2 + rr, gx = x0 - 2 + xl;
            uint4 v = make_uint4(0u,0u,0u,0u);
            if ((unsigned)gy < (unsigned)HH && (unsigned)gx < (unsigned)WW)
                v = *(const uint4*)&f2in[((size_t)gy*WW + gx)*32 + c8*8];
            *(uint4*)&f2t[(rr*20 + xl)*32 + ((c8 ^ (xl & 3))*8)] = v;
        }
    }

    // conv3 weights (held across group loop)
    f16x8 W3f[9][2];
#pragma unroll
    for (int tap = 0; tap < 9; tap++)
#pragma unroll
        for (int t = 0; t < 2; t++)
            W3f[tap][t] = *(const f16x8*)&w3p[(tap*32 + t*16 + l16)*32 + quad*8];
    __syncthreads();

    // conv3: 21 groups of 16 px over 324 px (18x18) -> f3t
    for (int g = w; g < 21; g += 4) {
        int p = g*16 + l16;
        bool pin = p < 324;
        int pc = pin ? p : 323;
        int rr = pc / 18, xl = pc - rr*18;
        f32x4 a3[2];
        a3[0] = *(const f32x4*)&b3[quad*4];
        a3[1] = *(const f32x4*)&b3[16 + quad*4];
#pragma unroll
        for (int tap = 0; tap < 9; tap++) {
            int dy = tap / 3, dx = tap - dy*3;
            int rr2 = rr + dy, xl2 = xl + dx;
            f16x8 b = *(const f16x8*)&f2t[(rr2*20 + xl2)*32 + ((quad ^ (xl2 & 3))*8)];
            a3[0] = __builtin_amdgcn_mfma_f32_16x16x32_f16(W3f[tap][0], b, a3[0], 0,0,0);
            a3[1] = __builtin_amdgcn_mfma_f32_16x16x32_f16(W3f[tap][1], b, a3[1], 0,0,0);
        }
        int fy = ytile - 1 + rr, fx = x0 - 1 + xl;
        bool img = (unsigned)fy < (unsigned)HH && (unsigned)fx < (unsigned)WW;
        if (pin) {
#pragma unroll
            for (int t = 0; t < 2; t++) {
                f16x4 h;
#pragma unroll
                for (int r4 = 0; r4 < 4; r4++) {
                    float v = a3[t][r4];
                    v = (v >= 0.f) ? v : alpha*v;
                    h[r4] = img ? (f16)v : (f16)0.f;
                }
                int c8w = t*2 + (quad >> 1);
                *(f16x4*)&f3t[p*32 + ((c8w ^ (xl & 3))*8) + (quad & 1)*4] = h;
            }
        }
    }
    __syncthreads();

    // conv4: wave w -> out rows 4w..4w+3; nt=3; dy-outer weight frags
    f32x4 a4[4][3];
    {
        f32x4 c0 = *(const f32x4*)&b4[quad*4];
        f32x4 c1 = *(const f32x4*)&b4[16 + quad*4];
        f32x4 c2;
#pragma unroll
        for (int r4 = 0; r4 < 4; r4++) {
            int co = 32 + quad*4 + r4;
            c2[r4] = (co < 37) ? b4[co] : 0.f;
        }
#pragma unroll
        for (int i = 0; i < 4; i++) { a4[i][0] = c0; a4[i][1] = c1; a4[i][2] = c2; }
    }
#pragma unroll
    for (int dy = 0; dy < 3; dy++) {
        f16x8 W4f[3][3];
#pragma unroll
        for (int dx = 0; dx < 3; dx++)
#pragma unroll
            for (int t = 0; t < 3; t++)
                W4f[dx][t] = *(const f16x8*)&w4p[((dy*3+dx)*48 + t*16 + l16)*32 + quad*8];
#pragma unroll
        for (int i = 0; i < 4; i++) {
            int rr = 4*w + i + dy;
#pragma unroll
            for (int dx = 0; dx < 3; dx++) {
                int xl = l16 + dx;
                f16x8 b = *(const f16x8*)&f3t[(rr*18 + xl)*32 + ((quad ^ (xl & 3))*8)];
#pragma unroll
                for (int t = 0; t < 3; t++)
                    a4[i][t] = __builtin_amdgcn_mfma_f32_16x16x32_f16(W4f[dx][t], b, a4[i][t], 0,0,0);
            }
        }
    }
    __syncthreads();   // f3t dead; headb valid

    // W (37ch fp32) -> LDS [256 px][42]
#pragma unroll
    for (int i = 0; i < 4; i++) {
        float* dst = &headb[((4*w + i)*16 + l16)*42];
#pragma unroll
        for (int t = 0; t < 3; t++) {
            if (t < 2 || quad < 2) {
                int cb = t*16 + quad*4;
                *(float2*)&dst[cb]   = make_float2(a4[i][t][0], a4[i][t][1]);
                *(float2*)&dst[cb+2] = make_float2(a4[i][t][2], a4[i][t][3]);
            }
        }
    }
    __syncthreads();

    // head: 1 px/thread. k0=(-.25,.25) k1=(.25,.25) k2=(-.25,-.25) k3=(.25,-.25)
    {
        int rloc = tid >> 4, xx = tid & 15;
        int gy = ytile + rloc, gx = x0 + xx;
        if (gy < HH) {
            const float* Wp = &headb[tid*42];
            float base = Wp[36];
            float o0 = base, o1 = base, o2 = base, o3 = base;
#pragma unroll
            for (int j = 0; j < 12; j++) {
                float u  = Wp[2*j];
                float v  = Wp[2*j+1];
                float w1 = Wp[24+j];
                float s = 0.25f*(u+v);
                float d = 0.25f*(v-u);
                o0 += fmaxf(d, 0.f)*w1;
                o1 += fmaxf(s, 0.f)*w1;
                o2 += fmaxf(-s, 0.f)*w1;
                o3 += fmaxf(-d, 0.f)*w1;
            }
            *(float2*)(outp + (size_t)(2*gy)*(2*WW) + 2*gx)   = make_float2(o0, o1);
            *(float2*)(outp + (size_t)(2*gy+1)*(2*WW) + 2*gx) = make_float2(o2, o3);
        }
    }
}

extern "C" void kernel_launch(void* const* d_in, const int* in_sizes, int n_in,
                              void* d_out, int out_size, void* d_ws, size_t ws_size,
                              hipStream_t stream) {
    const float* x  = (const float*)d_in[0];
    const float* w1 = (const float*)d_in[1];
    const float* b1 = (const float*)d_in[2];
    const float* w2 = (const float*)d_in[3];
    const float* b2 = (const float*)d_in[4];
    const float* w3 = (const float*)d_in[5];
    const float* b3 = (const float*)d_in[6];
    const float* w4 = (const float*)d_in[7];
    const float* b4 = (const float*)d_in[8];
    const float* pa = (const float*)d_in[9];
    float* outp = (float*)d_out;

    char* ws = (char*)d_ws;
    f16* wpk = (f16*)ws;
    const f16* w1p = wpk;
    const f16* w2p = wpk + 2048;
    const f16* w3p = wpk + 2048 + 18432;
    const f16* w4p = wpk + 2048 + 18432 + 9216;
    f16* f2 = (f16*)(ws + 131072);   // 33,177,600 B

    prepack_k<<<dim3(170), 256, 0, stream>>>(w1, w2, w3, w4, wpk);

    const int NT = 34*60;   // 16-row x 16-px output tiles
    for (int b = 0; b < 4; b++) {
        fuseA_k<<<dim3(NT), 256, 0, stream>>>(x + (size_t)b*HWPIX, w1p, b1, w2p, b2, pa, f2);
        fuseB_k<<<dim3(NT), 256, 0, stream>>>(f2, w3p, b3, w4p, b4, pa, outp + (size_t)b*4*HWPIX);
    }
}

// Round 8
// 420.818 us; speedup vs baseline: 1.5759x; 1.1522x over previous
//
#include <hip/hip_runtime.h>

typedef _Float16 f16;
typedef f16  f16x8 __attribute__((ext_vector_type(8)));
typedef f16  f16x4 __attribute__((ext_vector_type(4)));
typedef float f32x4 __attribute__((ext_vector_type(4)));

#define HH 540
#define WW 960
#define HWPIX (HH*WW)

// ws layout (bytes):
//   wpk @ 0: prepacked f16 weights (w1p 4096 | w2p 36864 | w3p 18432 | w4p 27648)
//   f2[b] @ 131072 + b*33177600 : 4 batches x 33,177,600 B  (total ~132.8 MB)

// ------------------------------------------------------------ weight prepack
__global__ __launch_bounds__(256) void prepack_k(const float* __restrict__ w1,
        const float* __restrict__ w2, const float* __restrict__ w3,
        const float* __restrict__ w4, f16* __restrict__ ws) {
    int i = blockIdx.x*256 + threadIdx.x;
    f16* w1p = ws;
    f16* w2p = ws + 2048;
    f16* w3p = ws + 2048 + 18432;
    f16* w4p = ws + 2048 + 18432 + 9216;
    if (i < 2048) {
        int k = i & 31, co = i >> 5;
        w1p[i] = (f16)(k < 25 ? w1[co*25 + k] : 0.f);
    } else if (i < 2048 + 18432) {
        int j = i - 2048;
        int ci = j & 63; int rest = j >> 6; int co = rest & 31; int tap = rest >> 5;
        w2p[j] = (f16)w2[(co*64 + ci)*9 + tap];
    } else if (i < 2048 + 18432 + 9216) {
        int j = i - (2048 + 18432);
        int ci = j & 31; int rest = j >> 5; int co = rest & 31; int tap = rest >> 5;
        w3p[j] = (f16)w3[(co*32 + ci)*9 + tap];
    } else if (i < 2048 + 18432 + 9216 + 13824) {
        int j = i - (2048 + 18432 + 9216);
        int ci = j & 31; int rest = j >> 5; int co = rest % 48; int tap = rest / 48;
        w4p[j] = (f16)(co < 37 ? w4[(co*32 + ci)*9 + tap] : 0.f);
    }
}

// ------------------------------------------------------------ fuseA: conv1 + conv2
// blockIdx.y = batch. Out tile 16x16 of f2. x tile 22x22 f16 (origin -3,-3) ->
// conv1 (MFMA, A=weights 64co x K32) -> f1 LDS tile 18x18x64 (swizzled,
// out-of-image zeroed) -> conv2 (MFMA dy-reuse) -> f2 global (PReLU, packed).
__global__ __launch_bounds__(256, 3) void fuseA_k(const float* __restrict__ xbase,
        const f16* __restrict__ w1p, const float* __restrict__ b1,
        const f16* __restrict__ w2p, const float* __restrict__ b2,
        const float* __restrict__ pa, f16* __restrict__ f2base) {
    __shared__ __align__(16) f16 xt[22*24];
    __shared__ __align__(16) f16 f1t[324*64];
    const int tid = threadIdx.x;
    const int w = tid >> 6, lane = tid & 63, l16 = lane & 15, quad = lane >> 4;
    const int trow = blockIdx.x / 60, tcol = blockIdx.x % 60;
    const int ytile = trow*16, x0 = tcol*16;
    const int batch = blockIdx.y;
    const float* xin = xbase + (size_t)batch*HWPIX;
    f16* f2out = f2base + (size_t)batch*HWPIX*32;
    const float alpha = pa[0];

    // stage x tile as f16 (zero halo), row stride 24
    for (int i = tid; i < 484; i += 256) {
        int rr = i / 22, xl = i - rr*22;
        int gy = ytile - 3 + rr, gx = x0 - 3 + xl;
        float v = 0.f;
        if ((unsigned)gy < (unsigned)HH && (unsigned)gx < (unsigned)WW)
            v = xin[gy*WW + gx];
        xt[rr*24 + xl] = (f16)v;
    }

    // conv1 weight frags: A[m=co(l16 within t-tile)][k=quad*8+j]
    f16x8 W1f[4];
#pragma unroll
    for (int t = 0; t < 4; t++)
        W1f[t] = *(const f16x8*)&w1p[(t*16 + l16)*32 + quad*8];

    int tky[8], tkx[8]; bool tok[8];
#pragma unroll
    for (int j = 0; j < 8; j++) {
        int t = quad*8 + j;
        tok[j] = (t < 25);
        tky[j] = t / 5; tkx[j] = t - (t/5)*5;
    }
    __syncthreads();

    // conv1: 21 groups of 16 px over 324 px (18x18)
    for (int g = w; g < 21; g += 4) {
        int p = g*16 + l16;
        bool pin = p < 324;
        int pc = pin ? p : 323;
        int rr = pc / 18, xl = pc - rr*18;
        f16x8 a;
#pragma unroll
        for (int j = 0; j < 8; j++)
            a[j] = tok[j] ? xt[(rr + tky[j])*24 + xl + tkx[j]] : (f16)0.f;
        f32x4 acc1[4];
#pragma unroll
        for (int t = 0; t < 4; t++) acc1[t] = *(const f32x4*)&b1[t*16 + quad*4];
#pragma unroll
        for (int t = 0; t < 4; t++)
            acc1[t] = __builtin_amdgcn_mfma_f32_16x16x32_f16(W1f[t], a, acc1[t], 0,0,0);
        int fy = ytile - 1 + rr, fx = x0 - 1 + xl;
        bool img = (unsigned)fy < (unsigned)HH && (unsigned)fx < (unsigned)WW;
        if (pin) {
#pragma unroll
            for (int t = 0; t < 4; t++) {
                f16x4 h;
#pragma unroll
                for (int r4 = 0; r4 < 4; r4++) {
                    float v = acc1[t][r4];
                    v = (v >= 0.f) ? v : alpha*v;
                    h[r4] = img ? (f16)v : (f16)0.f;
                }
                int c8w = t*2 + (quad >> 1);
                *(f16x4*)&f1t[p*64 + ((c8w ^ (xl & 7))*8) + (quad & 1)*4] = h;
            }
        }
    }
    __syncthreads();

    // conv2: wave w -> out rows 4w..4w+3; kc-outer weights; dy-reuse
    f32x4 acc[4][2];
    {
        f32x4 c0 = *(const f32x4*)&b2[quad*4];
        f32x4 c1 = *(const f32x4*)&b2[16 + quad*4];
#pragma unroll
        for (int i = 0; i < 4; i++) { acc[i][0] = c0; acc[i][1] = c1; }
    }
#pragma unroll
    for (int kc = 0; kc < 2; kc++) {
        f16x8 Wf[9][2];
#pragma unroll
        for (int tap = 0; tap < 9; tap++)
#pragma unroll
            for (int t = 0; t < 2; t++)
                Wf[tap][t] = *(const f16x8*)&w2p[(tap*32 + t*16 + l16)*64 + kc*32 + quad*8];
#pragma unroll
        for (int pr = 0; pr < 6; pr++) {
            int rr = 4*w + pr;
#pragma unroll
            for (int dx = 0; dx < 3; dx++) {
                int xl = l16 + dx;
                f16x8 b = *(const f16x8*)&f1t[(rr*18 + xl)*64 + (((kc*4 + quad) ^ (xl & 7))*8)];
#pragma unroll
                for (int dy = 0; dy < 3; dy++) {
                    int i = pr - dy;
                    if (i >= 0 && i < 4) {
                        acc[i][0] = __builtin_amdgcn_mfma_f32_16x16x32_f16(Wf[dy*3+dx][0], b, acc[i][0], 0,0,0);
                        acc[i][1] = __builtin_amdgcn_mfma_f32_16x16x32_f16(Wf[dy*3+dx][1], b, acc[i][1], 0,0,0);
                    }
                }
            }
        }
    }
#pragma unroll
    for (int i = 0; i < 4; i++) {
        int r = ytile + 4*w + i;
        if (r < HH) {
            size_t bo = ((size_t)r*WW + x0 + l16)*32;
#pragma unroll
            for (int t = 0; t < 2; t++) {
                f16x4 h;
#pragma unroll
                for (int r4 = 0; r4 < 4; r4++) {
                    float v = acc[i][t][r4];
                    v = (v >= 0.f) ? v : alpha*v;
                    h[r4] = (f16)v;
                }
                *(f16x4*)&f2out[bo + t*16 + quad*4] = h;
            }
        }
    }
}

// ------------------------------------------------------------ fuseB: conv3 + conv4 + head
// blockIdx.y = batch. f2 tile 20x20x32 -> conv3 -> f3 LDS 18x18x32 -> conv4
// (dy-outer weights) -> head (fp32 LDS, aliases dead tiles) -> output.
__global__ __launch_bounds__(256, 3) void fuseB_k(const f16* __restrict__ f2base,
        const f16* __restrict__ w3p, const float* __restrict__ b3,
        const f16* __restrict__ w4p, const float* __restrict__ b4,
        const float* __restrict__ pa, float* __restrict__ outbase) {
    __shared__ __align__(16) char smem[46336];
    f16*   f2t   = (f16*)smem;             // 25600 B
    f16*   f3t   = (f16*)(smem + 25600);   // 20736 B
    float* headb = (float*)smem;           // 43008 B (valid after f3t dead)

    const int tid = threadIdx.x;
    const int w = tid >> 6, lane = tid & 63, l16 = lane & 15, quad = lane >> 4;
    const int trow = blockIdx.x / 60, tcol = blockIdx.x % 60;
    const int ytile = trow*16, x0 = tcol*16;
    const int batch = blockIdx.y;
    const f16* f2in = f2base + (size_t)batch*HWPIX*32;
    float* outp = outbase + (size_t)batch*4*HWPIX;
    const float alpha = pa[0];

    // stage f2 tile 20x20 (zero halo), swizzled
#pragma unroll
    for (int it = 0; it < 7; it++) {
        int i = it*256 + tid;
        if (i < 1600) {
            int c8 = i & 3; int rest = i >> 2; int xl = rest % 20; int rr = rest / 20;
            int gy = ytile - 2 + rr, gx = x0 - 2 + xl;
            uint4 v = make_uint4(0u,0u,0u,0u);
            if ((unsigned)gy < (unsigned)HH && (unsigned)gx < (unsigned)WW)
                v = *(const uint4*)&f2in[((size_t)gy*WW + gx)*32 + c8*8];
            *(uint4*)&f2t[(rr*20 + xl)*32 + ((c8 ^ (xl & 3))*8)] = v;
        }
    }

    // conv3 weights (held across group loop)
    f16x8 W3f[9][2];
#pragma unroll
    for (int tap = 0; tap < 9; tap++)
#pragma unroll
        for (int t = 0; t < 2; t++)
            W3f[tap][t] = *(const f16x8*)&w3p[(tap*32 + t*16 + l16)*32 + quad*8];
    __syncthreads();

    // conv3: 21 groups of 16 px over 324 px (18x18) -> f3t
    for (int g = w; g < 21; g += 4) {
        int p = g*16 + l16;
        bool pin = p < 324;
        int pc = pin ? p : 323;
        int rr = pc / 18, xl = pc - rr*18;
        f32x4 a3[2];
        a3[0] = *(const f32x4*)&b3[quad*4];
        a3[1] = *(const f32x4*)&b3[16 + quad*4];
#pragma unroll
        for (int tap = 0; tap < 9; tap++) {
            int dy = tap / 3, dx = tap - dy*3;
            int rr2 = rr + dy, xl2 = xl + dx;
            f16x8 b = *(const f16x8*)&f2t[(rr2*20 + xl2)*32 + ((quad ^ (xl2 & 3))*8)];
            a3[0] = __builtin_amdgcn_mfma_f32_16x16x32_f16(W3f[tap][0], b, a3[0], 0,0,0);
            a3[1] = __builtin_amdgcn_mfma_f32_16x16x32_f16(W3f[tap][1], b, a3[1], 0,0,0);
        }
        int fy = ytile - 1 + rr, fx = x0 - 1 + xl;
        bool img = (unsigned)fy < (unsigned)HH && (unsigned)fx < (unsigned)WW;
        if (pin) {
#pragma unroll
            for (int t = 0; t < 2; t++) {
                f16x4 h;
#pragma unroll
                for (int r4 = 0; r4 < 4; r4++) {
                    float v = a3[t][r4];
                    v = (v >= 0.f) ? v : alpha*v;
                    h[r4] = img ? (f16)v : (f16)0.f;
                }
                int c8w = t*2 + (quad >> 1);
                *(f16x4*)&f3t[p*32 + ((c8w ^ (xl & 3))*8) + (quad & 1)*4] = h;
            }
        }
    }
    __syncthreads();

    // conv4: wave w -> out rows 4w..4w+3; nt=3; dy-outer weight frags
    f32x4 a4[4][3];
    {
        f32x4 c0 = *(const f32x4*)&b4[quad*4];
        f32x4 c1 = *(const f32x4*)&b4[16 + quad*4];
        f32x4 c2;
#pragma unroll
        for (int r4 = 0; r4 < 4; r4++) {
            int co = 32 + quad*4 + r4;
            c2[r4] = (co < 37) ? b4[co] : 0.f;
        }
#pragma unroll
        for (int i = 0; i < 4; i++) { a4[i][0] = c0; a4[i][1] = c1; a4[i][2] = c2; }
    }
#pragma unroll
    for (int dy = 0; dy < 3; dy++) {
        f16x8 W4f[3][3];
#pragma unroll
        for (int dx = 0; dx < 3; dx++)
#pragma unroll
            for (int t = 0; t < 3; t++)
                W4f[dx][t] = *(const f16x8*)&w4p[((dy*3+dx)*48 + t*16 + l16)*32 + quad*8];
#pragma unroll
        for (int i = 0; i < 4; i++) {
            int rr = 4*w + i + dy;
#pragma unroll
            for (int dx = 0; dx < 3; dx++) {
                int xl = l16 + dx;
                f16x8 b = *(const f16x8*)&f3t[(rr*18 + xl)*32 + ((quad ^ (xl & 3))*8)];
#pragma unroll
                for (int t = 0; t < 3; t++)
                    a4[i][t] = __builtin_amdgcn_mfma_f32_16x16x32_f16(W4f[dx][t], b, a4[i][t], 0,0,0);
            }
        }
    }
    __syncthreads();   // f3t dead; headb valid

    // W (37ch fp32) -> LDS [256 px][42]
#pragma unroll
    for (int i = 0; i < 4; i++) {
        float* dst = &headb[((4*w + i)*16 + l16)*42];
#pragma unroll
        for (int t = 0; t < 3; t++) {
            if (t < 2 || quad < 2) {
                int cb = t*16 + quad*4;
                *(float2*)&dst[cb]   = make_float2(a4[i][t][0], a4[i][t][1]);
                *(float2*)&dst[cb+2] = make_float2(a4[i][t][2], a4[i][t][3]);
            }
        }
    }
    __syncthreads();

    // head: 1 px/thread. k0=(-.25,.25) k1=(.25,.25) k2=(-.25,-.25) k3=(.25,-.25)
    {
        int rloc = tid >> 4, xx = tid & 15;
        int gy = ytile + rloc, gx = x0 + xx;
        if (gy < HH) {
            const float* Wp = &headb[tid*42];
            float base = Wp[36];
            float o0 = base, o1 = base, o2 = base, o3 = base;
#pragma unroll
            for (int j = 0; j < 12; j++) {
                float u  = Wp[2*j];
                float v  = Wp[2*j+1];
                float w1 = Wp[24+j];
                float s = 0.25f*(u+v);
                float d = 0.25f*(v-u);
                o0 += fmaxf(d, 0.f)*w1;
                o1 += fmaxf(s, 0.f)*w1;
                o2 += fmaxf(-s, 0.f)*w1;
                o3 += fmaxf(-d, 0.f)*w1;
            }
            *(float2*)(outp + (size_t)(2*gy)*(2*WW) + 2*gx)   = make_float2(o0, o1);
            *(float2*)(outp + (size_t)(2*gy+1)*(2*WW) + 2*gx) = make_float2(o2, o3);
        }
    }
}

extern "C" void kernel_launch(void* const* d_in, const int* in_sizes, int n_in,
                              void* d_out, int out_size, void* d_ws, size_t ws_size,
                              hipStream_t stream) {
    const float* x  = (const float*)d_in[0];
    const float* w1 = (const float*)d_in[1];
    const float* b1 = (const float*)d_in[2];
    const float* w2 = (const float*)d_in[3];
    const float* b2 = (const float*)d_in[4];
    const float* w3 = (const float*)d_in[5];
    const float* b3 = (const float*)d_in[6];
    const float* w4 = (const float*)d_in[7];
    const float* b4 = (const float*)d_in[8];
    const float* pa = (const float*)d_in[9];
    float* outp = (float*)d_out;

    char* ws = (char*)d_ws;
    f16* wpk = (f16*)ws;
    const f16* w1p = wpk;
    const f16* w2p = wpk + 2048;
    const f16* w3p = wpk + 2048 + 18432;
    const f16* w4p = wpk + 2048 + 18432 + 9216;
    f16* f2 = (f16*)(ws + 131072);   // 4 x 33,177,600 B

    prepack_k<<<dim3(170), 256, 0, stream>>>(w1, w2, w3, w4, wpk);

    const int NT = 34*60;   // 16-row x 16-px output tiles per batch
    fuseA_k<<<dim3(NT, 4), 256, 0, stream>>>(x, w1p, b1, w2p, b2, pa, f2);
    fuseB_k<<<dim3(NT, 4), 256, 0, stream>>>(f2, w3p, b3, w4p, b4, pa, outp);
}